// Round 7
// baseline (257.389 us; speedup 1.0000x reference)
//
#include <hip/hip_runtime.h>
#include <stdint.h>

#define T_TOK 4096
#define DIN   2048
#define DQ    2048
#define DKV   2048
#define NOUT  (DQ + 2*DKV)         /* 6144 */
#define NA    4
#define RLORA 16
#define BM    256
#define BN    256
#define MPAD  (T_TOK + NA*BM)      /* 5120 */
#define MTILES (MPAD/BM)           /* 20 */
#define KX    (DIN + 64)           /* 2112 */
#define NKT   (KX/32)              /* 66 K-tiles of 32 */
#define KSPLIT 16
#define NTBLK (NOUT/BN)            /* 24 */
#define NWG   (MTILES*NTBLK)       /* 480 */

typedef unsigned short u16;
typedef __attribute__((ext_vector_type(8))) short short8;
typedef __attribute__((ext_vector_type(8))) u16 u16x8;
typedef __attribute__((ext_vector_type(4))) float f32x4;

__device__ __forceinline__ u16 f2bf(float f) {
  uint32_t u = __float_as_uint(f);
  u = (u + 0x7FFFu + ((u >> 16) & 1u)) >> 16;
  return (u16)u;
}
__device__ __forceinline__ float bf2f(u16 u) {
  return __uint_as_float(((uint32_t)u) << 16);
}

typedef __attribute__((address_space(3))) void lds_void;
typedef __attribute__((address_space(1))) void glb_void;

__device__ __forceinline__ void gl_lds16(const void* g, void* l) {
  __builtin_amdgcn_global_load_lds((const glb_void*)(uintptr_t)g,
                                   (lds_void*)(uint32_t)(uintptr_t)l, 16, 0, 0);
}

// ---------------------------------------------------------------------------
// Kernel 1: stable counting sort of tokens by adapter, padded to BM multiples.
// ---------------------------------------------------------------------------
__global__ void prep_kernel(const int* __restrict__ widx,
                            int* __restrict__ tok,
                            int* __restrict__ tileAdapter) {
  __shared__ int cnt[256][NA];
  __shared__ int total[NA];
  __shared__ int pad_off[NA];
  const int tid = threadIdx.x;
  const int CH = T_TOK / 256;  // 16
  const int base = tid * CH;
  int c[NA] = {0, 0, 0, 0};
  for (int i = 0; i < CH; i++) c[widx[base + i]]++;
  for (int a = 0; a < NA; a++) cnt[tid][a] = c[a];
  __syncthreads();
  if (tid < NA) {
    int s = 0;
    for (int i = 0; i < 256; i++) { int v = cnt[i][tid]; cnt[i][tid] = s; s += v; }
    total[tid] = s;
  }
  __syncthreads();
  if (tid == 0) {
    int off = 0;
    for (int a = 0; a < NA; a++) {
      pad_off[a] = off;
      int ntile = (total[a] + BM - 1) / BM;
      for (int tl = 0; tl < ntile; tl++) tileAdapter[off / BM + tl] = a;
      off += ntile * BM;
    }
    for (int tl = off / BM; tl < MTILES; tl++) tileAdapter[tl] = -1;
  }
  __syncthreads();
  for (int i = tid; i < MPAD; i += 256) tok[i] = -1;
  __syncthreads();
  int myoff[NA];
  for (int a = 0; a < NA; a++) myoff[a] = pad_off[a] + cnt[tid][a];
  for (int i = 0; i < CH; i++) {
    int a = widx[base + i];
    tok[myoff[a]++] = base + i;
  }
}

// ---------------------------------------------------------------------------
// Kernel 2: gather x rows into sorted order -> bf16 (cols 0..2047 of Xg).
// ---------------------------------------------------------------------------
__global__ void gather_kernel(const float* __restrict__ x,
                              const int* __restrict__ tok,
                              u16* __restrict__ Xg) {
  const int row = blockIdx.x;
  const int t = tok[row];
  const int tid = threadIdx.x;
  u16x8* dst = (u16x8*)(Xg + (size_t)row * KX);
  if (t < 0) {
    u16x8 z = {0, 0, 0, 0, 0, 0, 0, 0};
    dst[tid] = z;
    return;
  }
  const f32x4* src = (const f32x4*)(x + (size_t)t * DIN);
  f32x4 v0 = src[tid * 2];
  f32x4 v1 = src[tid * 2 + 1];
  u16x8 o;
  o[0] = f2bf(v0[0]); o[1] = f2bf(v0[1]); o[2] = f2bf(v0[2]); o[3] = f2bf(v0[3]);
  o[4] = f2bf(v1[0]); o[5] = f2bf(v1[1]); o[6] = f2bf(v1[2]); o[7] = f2bf(v1[3]);
  dst[tid] = o;
}

// ---------------------------------------------------------------------------
// Kernel 3: Xa partials.  Xa = Xg[:, :2048] @ A_qkv[a]  ([M x 48]).
// ---------------------------------------------------------------------------
__global__ __launch_bounds__(256) void xa_partial_kernel(
    const u16* __restrict__ Xg, const float* __restrict__ A_qkv,
    const int* __restrict__ tileAdapter, float* __restrict__ Ppart) {
  const int ks = blockIdx.y;
  const int ad = tileAdapter[blockIdx.x >> 1];
  const int a = ad < 0 ? 0 : ad;
  const int kb = ks * (DIN / KSPLIT);
  const int tid = threadIdx.x;
  const int rg = tid >> 2;
  const int jg = tid & 3;
  const int r0 = blockIdx.x * 128 + rg * 2;
  const int j0 = jg * 12;
  __shared__ float ldsA[64][56];
  float acc[2][12];
  #pragma unroll
  for (int r = 0; r < 2; r++)
    #pragma unroll
    for (int j = 0; j < 12; j++) acc[r][j] = 0.f;

  for (int kc = 0; kc < 2; kc++) {
    const int kbase = kb + kc * 64;
    for (int i = tid; i < 64 * 48; i += 256) {
      int kk = i / 48, j = i - kk * 48;
      ldsA[kk][j] = A_qkv[((size_t)a * DIN + kbase + kk) * (3 * RLORA) + j];
    }
    __syncthreads();
    u16x8 xr[2][8];
    #pragma unroll
    for (int r = 0; r < 2; r++)
      #pragma unroll
      for (int q = 0; q < 8; q++)
        xr[r][q] = *(const u16x8*)(Xg + (size_t)(r0 + r) * KX + kbase + q * 8);
    #pragma unroll
    for (int q = 0; q < 8; q++) {
      #pragma unroll
      for (int e = 0; e < 8; e++) {
        const int kk = q * 8 + e;
        f32x4 a0 = *(const f32x4*)&ldsA[kk][j0];
        f32x4 a1 = *(const f32x4*)&ldsA[kk][j0 + 4];
        f32x4 a2 = *(const f32x4*)&ldsA[kk][j0 + 8];
        float x0 = bf2f(xr[0][q][e]);
        float x1 = bf2f(xr[1][q][e]);
        #pragma unroll
        for (int c = 0; c < 4; c++) {
          acc[0][c]     += x0 * a0[c];  acc[1][c]     += x1 * a0[c];
          acc[0][4 + c] += x0 * a1[c];  acc[1][4 + c] += x1 * a1[c];
          acc[0][8 + c] += x0 * a2[c];  acc[1][8 + c] += x1 * a2[c];
        }
      }
    }
    __syncthreads();
  }
  #pragma unroll
  for (int r = 0; r < 2; r++)
    #pragma unroll
    for (int j = 0; j < 12; j++)
      Ppart[((size_t)ks * MPAD + r0 + r) * 48 + j0 + j] = acc[r][j];
}

// ---------------------------------------------------------------------------
// Kernel 4: reduce partials -> bf16 into Xg cols 2048..2111 (j>=48 zero).
// ---------------------------------------------------------------------------
__global__ void xa_reduce_kernel(const float* __restrict__ Ppart,
                                 u16* __restrict__ Xg) {
  const int gid = blockIdx.x * 256 + threadIdx.x;
  const int row = gid >> 6, j = gid & 63;
  float s = 0.f;
  if (j < 48) {
    #pragma unroll
    for (int sp = 0; sp < KSPLIT; sp++)
      s += Ppart[((size_t)sp * MPAD + row) * 48 + j];
  }
  Xg[(size_t)row * KX + DIN + j] = f2bf(s);
}

// ---------------------------------------------------------------------------
// Kernel 5: Weff[a][n][k] = W_base[n][k] + Delta[a][k][n], bf16, k<2048.
// Software-pipelined across adapters.
// ---------------------------------------------------------------------------
__global__ __launch_bounds__(256) void weff2_kernel(
    const float* __restrict__ W_base,
    const float* __restrict__ DW_q, const float* __restrict__ DW_kv,
    u16* __restrict__ Weff) {
  const int k0 = blockIdx.x * 64;
  const int n0 = blockIdx.y * 64;
  const int tid = threadIdx.x;
  const int k8 = (tid & 7) * 8;
  __shared__ float ldsD[64][65];

  f32x4 wb[2][2];
  #pragma unroll
  for (int h = 0; h < 2; h++) {
    const int nn = h * 32 + (tid >> 3);
    const float* p = W_base + (size_t)(n0 + nn) * DIN + k0 + k8;
    wb[h][0] = *(const f32x4*)p;
    wb[h][1] = *(const f32x4*)(p + 4);
  }

  const int ldD  = (n0 < DQ) ? DQ : 2 * DKV;
  const int ncol = (n0 < DQ) ? n0 : n0 - DQ;
  const float* Dbase = (n0 < DQ) ? (DW_q + ncol) : (DW_kv + ncol);
  const size_t Dstride = (n0 < DQ) ? (size_t)DIN * DQ : (size_t)DIN * (2 * DKV);

  const int lkk = tid >> 6;     // 0..3
  const int lnn = tid & 63;

  float v[16];
  {
    const float* Dp = Dbase;
    #pragma unroll
    for (int j = 0; j < 16; j++)
      v[j] = Dp[(size_t)(k0 + lkk + 4 * j) * ldD + lnn];
  }

  for (int a = 0; a < NA; a++) {
    #pragma unroll
    for (int j = 0; j < 16; j++) ldsD[lkk + 4 * j][lnn] = v[j];
    if (a < NA - 1) {
      const float* Dp = Dbase + (size_t)(a + 1) * Dstride;
      #pragma unroll
      for (int j = 0; j < 16; j++)
        v[j] = Dp[(size_t)(k0 + lkk + 4 * j) * ldD + lnn];
    }
    __syncthreads();
    #pragma unroll
    for (int h = 0; h < 2; h++) {
      const int nn = h * 32 + (tid >> 3);
      u16x8 o;
      #pragma unroll
      for (int j = 0; j < 8; j++)
        o[j] = f2bf(wb[h][j >> 2][j & 3] + ldsD[k8 + j][nn]);
      *(u16x8*)(Weff + ((size_t)a * NOUT + n0 + nn) * KX + k0 + k8) = o;
    }
    __syncthreads();
  }
}

// ---------------------------------------------------------------------------
// Kernel 6: fill Weff[a][n][2048..2111] with scattered B (LoRA slots).
// ---------------------------------------------------------------------------
__global__ void wslots_kernel(const float* __restrict__ B_q,
                              const float* __restrict__ B_kv,
                              u16* __restrict__ Weff) {
  const int a = blockIdx.y;
  const int n = blockIdx.x * 256 + threadIdx.x;
  const int seg = n >> 11;   // 0=q, 1=k, 2=v
  u16 vals[64];
  #pragma unroll
  for (int j = 0; j < 64; j++) vals[j] = 0;
  if (seg == 0) {
    const float* Bp = B_q + ((size_t)a * RLORA) * DQ + n;
    #pragma unroll
    for (int r = 0; r < RLORA; r++) vals[r] = f2bf(Bp[(size_t)r * DQ]);
  } else if (seg == 1) {
    const float* Bp = B_kv + ((size_t)a * RLORA) * (2 * DKV) + (n - DQ);
    #pragma unroll
    for (int r = 0; r < RLORA; r++) vals[RLORA + r] = f2bf(Bp[(size_t)r * (2 * DKV)]);
  } else {
    const float* Bp = B_kv + ((size_t)a * RLORA) * (2 * DKV) + (n - DQ);
    #pragma unroll
    for (int r = 0; r < RLORA; r++) vals[2 * RLORA + r] = f2bf(Bp[(size_t)r * (2 * DKV)]);
  }
  u16* dst = Weff + ((size_t)a * NOUT + n) * KX + DIN;
  #pragma unroll
  for (int v = 0; v < 8; v++) *(u16x8*)(dst + v * 8) = *(u16x8*)(vals + v * 8);
}

// ---------------------------------------------------------------------------
// Kernel 7: grouped GEMM, 256x256 tile, BK=32, 8 waves (2Mx4N).
// HYBRID: 4-buffer circular pipeline (3-tile lookahead, counted vmcnt(8))
// + fine 2-phase interleave per tile {8 rd + 2 st | bar | 16 MFMA} x2.
// out[tok[m]] = Xg[m] @ Weff[a]^T  (bf16 MFMA 16x16x32)
// ---------------------------------------------------------------------------
#define BAR      asm volatile("s_barrier" ::: "memory")
#define WAITV(n) asm volatile("s_waitcnt vmcnt(" #n ")" ::: "memory")

// A buffers: elem b*8192 (16KB each, rows 64B). B buffers: elem 32768 + b*8192.
#define RD_A4(b, mlo) { \
  _Pragma("unroll") for (int q = 0; q < 4; ++q) { \
    const char* rp = ldsc + (b)*16384 + (wm*128 + ((mlo)+q)*16)*64; \
    af[(mlo)+q] = *(const short8*)(rp + laneoff); } }

#define RD_B4(b) { \
  _Pragma("unroll") for (int q = 0; q < 4; ++q) { \
    const char* rp = ldsc + 65536 + (b)*16384 + (wn*64 + q*16)*64; \
    bfr[q] = *(const short8*)(rp + laneoff); } }

#define ST_U01(b, t) { \
  gl_lds16(gAsrc + (size_t)(t)*32, ldsu + (b)*8192 + stid); \
  gl_lds16(gAsrc + (size_t)128*KX + (size_t)(t)*32, ldsu + (b)*8192 + 4096 + stid); }

#define ST_U23(b, t) { \
  gl_lds16(gBsrc + (size_t)(t)*32, ldsu + 32768 + (b)*8192 + stid); \
  gl_lds16(gBsrc + (size_t)128*KX + (size_t)(t)*32, ldsu + 32768 + (b)*8192 + 4096 + stid); }

#define MM4(mlo) { \
  __builtin_amdgcn_s_setprio(1); \
  _Pragma("unroll") for (int mi = 0; mi < 4; ++mi) \
  _Pragma("unroll") for (int ni = 0; ni < 4; ++ni) \
    acc[(mlo)+mi][ni] = __builtin_amdgcn_mfma_f32_16x16x32_bf16( \
        af[(mlo)+mi], bfr[ni], acc[(mlo)+mi][ni], 0, 0, 0); \
  __builtin_amdgcn_s_setprio(0); }

// full tile with staging of tile t+3 into buffer (b+3)&3
#define TILE(b, t, W) { \
  W; BAR; \
  RD_A4(b, 0); RD_B4(b); ST_U01(((b)+3)&3, (t)+3); \
  BAR; \
  MM4(0); \
  RD_A4(b, 4); ST_U23(((b)+3)&3, (t)+3); \
  BAR; \
  MM4(4); }

// tail tile, no staging
#define TILE_N(b, W) { \
  W; BAR; \
  RD_A4(b, 0); RD_B4(b); \
  BAR; \
  MM4(0); \
  RD_A4(b, 4); \
  BAR; \
  MM4(4); }

__global__ __launch_bounds__(512, 2) void gemm256_kernel(
    const u16* __restrict__ Xg, const u16* __restrict__ Weff,
    const int* __restrict__ tok, const int* __restrict__ tileAdapter,
    float* __restrict__ out) {
  __shared__ __align__(16) u16 Lds[65536];   // A[4][256*32] | B[4][256*32]

  // XCD-chunked linear id, then same-adapter mt-pair-major tile order.
  const int bid = blockIdx.x;
  const int lw = (bid & 7) * (NWG / 8) + (bid >> 3);
  const int pg  = lw / (2 * NTBLK);
  const int rem = lw % (2 * NTBLK);
  const int nt  = rem >> 1;
  const int mt  = pg * 2 + (rem & 1);
  const int a = tileAdapter[mt];
  if (a < 0) return;
  const int m0 = mt * BM, n0 = nt * BN;

  const int tid = threadIdx.x;
  const int l = tid & 63, w = tid >> 6;
  const int wm = w >> 2, wn = w & 3;
  const int fr = l & 15;
  // read: row fr (within frag), 16B chunk (l>>4) ^ ((fr>>1)&3)  [2-way free]
  const int laneoff = fr * 64 + ((((l >> 4) ^ ((fr >> 1) & 3))) << 4);

  // staging: thread covers row tid>>2, source chunk pre-swizzled
  const int srow = tid >> 2;
  const int scol = (((tid & 3) ^ ((tid >> 3) & 3))) * 8;
  const int stid = tid * 8;
  const u16* gAsrc = Xg + (size_t)(m0 + srow) * KX + scol;
  const u16* gBsrc = Weff + ((size_t)a * NOUT + n0 + srow) * KX + scol;

  u16* ldsu = &Lds[0];
  const char* ldsc = (const char*)ldsu;

  f32x4 acc[8][4];
  #pragma unroll
  for (int i = 0; i < 8; i++)
    #pragma unroll
    for (int j = 0; j < 4; j++) acc[i][j] = (f32x4){0.f, 0.f, 0.f, 0.f};

  short8 af[8], bfr[4];

  // prologue: stage tiles 0,1,2 (12 loads in flight)
  ST_U01(0, 0); ST_U23(0, 0);
  ST_U01(1, 1); ST_U23(1, 1);
  ST_U01(2, 2); ST_U23(2, 2);

  // main: tiles 0..59 in groups of 4 (static buffer ids)
  for (int p = 0; p < 15; ++p) {
    const int t4 = 4 * p;
    TILE(0, t4 + 0, WAITV(8));
    TILE(1, t4 + 1, WAITV(8));
    TILE(2, t4 + 2, WAITV(8));
    TILE(3, t4 + 3, WAITV(8));
  }
  // tiles 60,61,62 still stage 63,64,65
  TILE(0, 60, WAITV(8));
  TILE(1, 61, WAITV(8));
  TILE(2, 62, WAITV(8));
  // tail tiles 63,64,65: drain 8 -> 4 -> 0
  TILE_N(3, WAITV(8));
  TILE_N(0, WAITV(4));
  TILE_N(1, WAITV(0));

  // C-write: scatter rows via tok
  #pragma unroll
  for (int mi = 0; mi < 8; ++mi) {
    const int rb = m0 + wm * 128 + mi * 16 + ((l >> 4) << 2);
    int tt[4];
    #pragma unroll
    for (int reg = 0; reg < 4; ++reg) tt[reg] = tok[rb + reg];
    #pragma unroll
    for (int ni = 0; ni < 4; ++ni) {
      const int col = n0 + wn * 64 + ni * 16 + fr;
      #pragma unroll
      for (int reg = 0; reg < 4; ++reg)
        if (tt[reg] >= 0) out[(size_t)tt[reg] * NOUT + col] = acc[mi][ni][reg];
    }
  }
}

// ---------------------------------------------------------------------------
// Fallback (ws too small): correct fp32 path.
// ---------------------------------------------------------------------------
__global__ void fallback_kernel(const float* __restrict__ x,
                                const float* __restrict__ W_base,
                                const float* __restrict__ A_qkv,
                                const float* __restrict__ B_q,
                                const float* __restrict__ B_kv,
                                const float* __restrict__ DW_q,
                                const float* __restrict__ DW_kv,
                                const int* __restrict__ widx,
                                float* __restrict__ out) {
  const int t = blockIdx.x;
  const int n = blockIdx.y * 256 + threadIdx.x;
  const int a = widx[t];
  __shared__ float xs[DIN];
  __shared__ float ys[3 * RLORA];
  for (int k = threadIdx.x; k < DIN; k += 256) xs[k] = x[(size_t)t * DIN + k];
  __syncthreads();
  if (threadIdx.x < 3 * RLORA) {
    float s = 0.f;
    const float* Ap = A_qkv + (size_t)a * DIN * (3 * RLORA) + threadIdx.x;
    for (int k = 0; k < DIN; k++) s += xs[k] * Ap[(size_t)k * (3 * RLORA)];
    ys[threadIdx.x] = s;
  }
  __syncthreads();
  const float* dcol; int ldD, roff; const float* bcol; int ldB;
  if (n < DQ) {
    dcol = DW_q + (size_t)a * DIN * DQ + n; ldD = DQ; roff = 0;
    bcol = B_q + (size_t)a * RLORA * DQ + n; ldB = DQ;
  } else {
    dcol = DW_kv + (size_t)a * DIN * (2 * DKV) + (n - DQ); ldD = 2 * DKV;
    roff = (n < 2 * DQ) ? RLORA : 2 * RLORA;
    bcol = B_kv + (size_t)a * RLORA * (2 * DKV) + (n - DQ); ldB = 2 * DKV;
  }
  const float* wrow = W_base + (size_t)n * DIN;
  float acc = 0.f;
  for (int k = 0; k < DIN; k++) acc += xs[k] * (wrow[k] + dcol[(size_t)k * ldD]);
  for (int r = 0; r < RLORA; r++) acc += ys[roff + r] * bcol[(size_t)r * ldB];
  out[(size_t)t * NOUT + n] = acc;
}

// ---------------------------------------------------------------------------
extern "C" void kernel_launch(void* const* d_in, const int* in_sizes, int n_in,
                              void* d_out, int out_size, void* d_ws, size_t ws_size,
                              hipStream_t stream) {
  const float* x      = (const float*)d_in[0];
  const float* W_base = (const float*)d_in[1];
  const float* A_qkv  = (const float*)d_in[2];
  const float* B_q    = (const float*)d_in[3];
  const float* B_kv   = (const float*)d_in[4];
  const float* DW_q   = (const float*)d_in[5];
  const float* DW_kv  = (const float*)d_in[6];
  const int*   widx   = (const int*)d_in[7];
  float* out = (float*)d_out;

  const size_t WEFF_BYTES = (size_t)NA * NOUT * KX * sizeof(u16);
  const size_t XG_BYTES   = (size_t)MPAD * KX * sizeof(u16);
  const size_t TOK_BYTES  = (size_t)MPAD * sizeof(int);
  const size_t TILE_BYTES = (size_t)MTILES * sizeof(int);
  const size_t need = WEFF_BYTES + XG_BYTES + TOK_BYTES + TILE_BYTES;

  if (ws_size < need) {
    fallback_kernel<<<dim3(T_TOK, NOUT / 256), 256, 0, stream>>>(
        x, W_base, A_qkv, B_q, B_kv, DW_q, DW_kv, widx, out);
    return;
  }

  char* ws = (char*)d_ws;
  u16* Weff = (u16*)ws;
  u16* Xg   = (u16*)(ws + WEFF_BYTES);
  int* tok  = (int*)(ws + WEFF_BYTES + XG_BYTES);
  int* tileAdapter = tok + MPAD;
  float* Ppart = (float*)ws;   // aliases Weff; consumed before weff2 writes

  prep_kernel<<<1, 256, 0, stream>>>(widx, tok, tileAdapter);
  gather_kernel<<<MPAD, 256, 0, stream>>>(x, tok, Xg);
  xa_partial_kernel<<<dim3(MPAD / 128, KSPLIT), 256, 0, stream>>>(
      Xg, A_qkv, tileAdapter, Ppart);
  xa_reduce_kernel<<<MPAD * 64 / 256, 256, 0, stream>>>(Ppart, Xg);
  weff2_kernel<<<dim3(DIN / 64, NOUT / 64), 256, 0, stream>>>(
      W_base, DW_q, DW_kv, Weff);
  wslots_kernel<<<dim3(NOUT / 256, NA), 256, 0, stream>>>(B_q, B_kv, Weff);
  gemm256_kernel<<<dim3(NWG), 512, 0, stream>>>(
      Xg, Weff, tok, tileAdapter, out);
}